// Round 1
// baseline (1499.582 us; speedup 1.0000x reference)
//
#include <hip/hip_runtime.h>

// ---- problem constants -----------------------------------------------------
constexpr int N_ = 64, C_ = 64, T_ = 300, V_ = 25, IC_ = 16, S_ = 3, KT_ = 9;
constexpr int RCH = 8, RSUB = 60;       // attention split-K chunks / LDS sub-chunk rows
constexpr int TT_A = 10, CC_A = 16;     // tconv: t-tile, channel chunk
constexpr int TT_C = 10, CC_C = 32;     // agg_out: t-tile, channel chunk
constexpr int XPAD = 28;                // padded LDS row stride (16B-aligned rows for b128)

// ---- workspace layout (floats); total = 15,869,747 floats ~= 63.5 MB -------
constexpr int OFF_AFULL = 0;
constexpr int SZ_AFULL  = S_ * V_ * V_;              // 1875
constexpr int OFF_W1S   = OFF_AFULL + SZ_AFULL;
constexpr int SZ_WTS    = S_ * C_ * KT_ * IC_;       // 27648, layout [i][c][kt][o]
constexpr int OFF_W2S   = OFF_W1S + SZ_WTS;
constexpr int OFF_WDS   = OFF_W2S + SZ_WTS;
constexpr int SZ_WDS    = S_ * C_ * C_;              // 12288, layout [i][c][o]
constexpr int OFF_BT1   = OFF_WDS + SZ_WDS;          // S*IC
constexpr int OFF_BT2   = OFF_BT1 + S_ * IC_;
constexpr int OFF_BDT   = OFF_BT2 + S_ * IC_;        // C
constexpr int OFF_BNA   = OFF_BDT + C_;
constexpr int OFF_BNB   = OFF_BNA + C_;
constexpr int OFF_A1    = OFF_BNB + C_;
constexpr int SZ_A1     = S_ * N_ * V_ * V_;         // 120000
constexpr int OFF_SPART = OFF_A1 + SZ_A1;
constexpr int SZ_SPART  = N_ * RCH * V_ * V_;        // 320000
constexpr int OFF_T1    = OFF_SPART + SZ_SPART;
constexpr int SZ_T      = N_ * IC_ * T_ * V_;        // 7680000
constexpr int OFF_T2    = OFF_T1 + SZ_T;

// SlimConv2d channel scales: splits at int(0.6/0.7/0.8/0.9 * out_c)
__device__ __forceinline__ float slim16(const float* w, int o) {
    if (o < 9)  return 1.0f;   // int(0.6*16)=9
    if (o < 11) return w[1];   // int(0.7*16)=11
    if (o < 12) return w[2];   // int(0.8*16)=12
    if (o < 14) return w[3];   // int(0.9*16)=14
    return w[4];
}
__device__ __forceinline__ float slim64(const float* w, int o) {
    if (o < 38) return 1.0f;   // int(0.6*64)=38
    if (o < 44) return w[1];   // int(0.7*64)=44
    if (o < 51) return w[2];   // int(0.8*64)=51
    if (o < 57) return w[3];   // int(0.9*64)=57
    return w[4];
}

// ---- prep: A_full, scaled/transposed weights, folded biases, BN affine -----
__global__ void prep_kernel(const float* __restrict__ wv,  const float* __restrict__ A,
                            const float* __restrict__ PA,  const float* __restrict__ Wd,
                            const float* __restrict__ bd,  const float* __restrict__ WT1,
                            const float* __restrict__ bT1, const float* __restrict__ WT2,
                            const float* __restrict__ bT2, const float* __restrict__ gam,
                            const float* __restrict__ bet, const float* __restrict__ mu,
                            const float* __restrict__ var, float* __restrict__ ws)
{
    const int gid = blockIdx.x * blockDim.x + threadIdx.x;
    const int stride = gridDim.x * blockDim.x;
    // A_full = A + PA + 8A^4 - 4A^2 - 4A + I (elementwise powers)
    for (int idx = gid; idx < S_ * V_ * V_; idx += stride) {
        int uv = idx % (V_ * V_);
        int u = uv / V_, v = uv % V_;
        float a  = A[idx];
        float a2 = a * a;
        ws[OFF_AFULL + idx] = a + PA[idx] + 8.f * a2 * a2 - 4.f * a2 - 4.f * a
                              + (u == v ? 1.f : 0.f);
    }
    // temporal conv weights, scaled, layout [i][c][kt][o] (o contiguous for s_load)
    for (int idx = gid; idx < SZ_WTS; idx += stride) {
        int o  = idx % IC_;
        int kt = (idx / IC_) % KT_;
        int c  = (idx / (IC_ * KT_)) % C_;
        int i  = idx / (IC_ * KT_ * C_);
        float s = slim16(wv, o);
        int src = ((i * IC_ + o) * C_ + c) * KT_ + kt;
        ws[OFF_W1S + idx] = s * WT1[src];
        ws[OFF_W2S + idx] = s * WT2[src];
    }
    // 1x1 conv weights, scaled, transposed to [i][c][o]
    for (int idx = gid; idx < SZ_WDS; idx += stride) {
        int o = idx % C_;
        int c = (idx / C_) % C_;
        int i = idx / (C_ * C_);
        ws[OFF_WDS + idx] = slim64(wv, o) * Wd[(i * C_ + o) * C_ + c];
    }
    // scaled t-conv biases [i][o]
    for (int idx = gid; idx < S_ * IC_; idx += stride) {
        float s = slim16(wv, idx % IC_);
        ws[OFF_BT1 + idx] = s * bT1[idx];
        ws[OFF_BT2 + idx] = s * bT2[idx];
    }
    // summed scaled 1x1 bias + BN affine
    for (int idx = gid; idx < C_; idx += stride) {
        float bt = 0.f;
        for (int i = 0; i < S_; ++i) bt += slim64(wv, idx) * bd[i * C_ + idx];
        ws[OFF_BDT + idx] = bt;
        float ba = gam[idx] * rsqrtf(var[idx] + 1e-5f);
        ws[OFF_BNA + idx] = ba;
        ws[OFF_BNB + idx] = bet[idx] - mu[idx] * ba;
    }
}

// ---- kernel A: both temporal convs (t1,t2) for one subset ------------------
// thread=(t,v); 32 accumulators; x tile in LDS; weights via uniform scalar loads
__global__ __launch_bounds__(256) void tconv_kernel(
    const float* __restrict__ x,  const float* __restrict__ w1,
    const float* __restrict__ w2, const float* __restrict__ b1,
    const float* __restrict__ b2, float* __restrict__ t1o, float* __restrict__ t2o)
{
    __shared__ float xs[CC_A * (TT_A + 8) * V_];   // 7200 floats = 28.8 KB
    const int tid = threadIdx.x;
    const int n   = blockIdx.y;
    const int t0  = blockIdx.x * TT_A;
    const int tl  = tid / V_;
    const int v   = tid % V_;
    float acc1[IC_], acc2[IC_];
#pragma unroll
    for (int o = 0; o < IC_; ++o) { acc1[o] = b1[o]; acc2[o] = b2[o]; }

    for (int ch = 0; ch < C_ / CC_A; ++ch) {
        __syncthreads();
        for (int idx = tid; idx < CC_A * (TT_A + 8) * V_; idx += 256) {
            int c   = idx / ((TT_A + 8) * V_);
            int rem = idx % ((TT_A + 8) * V_);
            int tg  = t0 - 4 + rem / V_;
            int vv  = rem % V_;
            float val = 0.f;
            if (tg >= 0 && tg < T_)
                val = x[((n * C_ + ch * CC_A + c) * T_ + tg) * V_ + vv];
            xs[idx] = val;
        }
        __syncthreads();
        if (tl < TT_A) {
            for (int c = 0; c < CC_A; ++c) {
#pragma unroll
                for (int kt = 0; kt < KT_; ++kt) {
                    const float xv = xs[(c * (TT_A + 8) + tl + kt) * V_ + v];
                    const float* __restrict__ p1 = w1 + ((ch * CC_A + c) * KT_ + kt) * IC_;
                    const float* __restrict__ p2 = w2 + ((ch * CC_A + c) * KT_ + kt) * IC_;
#pragma unroll
                    for (int o = 0; o < IC_; ++o) {
                        acc1[o] = fmaf(p1[o], xv, acc1[o]);
                        acc2[o] = fmaf(p2[o], xv, acc2[o]);
                    }
                }
            }
        }
    }
    if (tl < TT_A) {
        const int tg = t0 + tl;
#pragma unroll
        for (int o = 0; o < IC_; ++o) {
            t1o[((n * IC_ + o) * T_ + tg) * V_ + v] = acc1[o];
            t2o[((n * IC_ + o) * T_ + tg) * V_ + v] = acc2[o];
        }
    }
}

// ---- kernel B1: attention partial sums S[u,v] over 600-row chunks ----------
__global__ __launch_bounds__(256) void att_partial_kernel(
    const float* __restrict__ t1, const float* __restrict__ t2,
    float* __restrict__ spart)
{
    __shared__ float t1s[RSUB * V_];
    __shared__ float t2s[RSUB * V_];
    const int tid = threadIdx.x;
    const int rc  = blockIdx.x;
    const int n   = blockIdx.y;
    const int p0 = tid, p1 = tid + 256, p2 = tid + 512;
    const int p2c = (p2 < V_ * V_) ? p2 : (V_ * V_ - 1);
    const int u0 = p0 / V_, v0 = p0 % V_;
    const int u1 = p1 / V_, v1 = p1 % V_;
    const int u2 = p2c / V_, v2 = p2c % V_;
    float a0 = 0.f, a1 = 0.f, a2 = 0.f;
    const int rows = (IC_ * T_) / RCH;                       // 600
    const float* g1 = t1 + n * (IC_ * T_ * V_) + rc * rows * V_;
    const float* g2 = t2 + n * (IC_ * T_ * V_) + rc * rows * V_;
    for (int sc = 0; sc < rows / RSUB; ++sc) {
        __syncthreads();
        for (int idx = tid; idx < RSUB * V_; idx += 256) {
            t1s[idx] = g1[sc * RSUB * V_ + idx];
            t2s[idx] = g2[sc * RSUB * V_ + idx];
        }
        __syncthreads();
        for (int r = 0; r < RSUB; ++r) {
            const float* r1 = t1s + r * V_;
            const float* r2 = t2s + r * V_;
            a0 = fmaf(r1[u0], r2[v0], a0);
            a1 = fmaf(r1[u1], r2[v1], a1);
            a2 = fmaf(r1[u2], r2[v2], a2);
        }
    }
    float* sp = spart + (n * RCH + rc) * (V_ * V_);
    sp[p0] = a0;
    sp[p1] = a1;
    if (p2 < V_ * V_) sp[p2] = a2;
}

// ---- kernel B2: combine partials, softmax over u (axis=-2), add A_full -----
__global__ __launch_bounds__(256) void att_softmax_kernel(
    const float* __restrict__ spart, const float* __restrict__ afull,
    float* __restrict__ a1o)
{
    __shared__ float Ss[V_ * V_];
    const int n = blockIdx.x;
    const int tid = threadIdx.x;
    for (int p = tid; p < V_ * V_; p += 256) {
        float s = 0.f;
        for (int rc = 0; rc < RCH; ++rc)
            s += spart[(n * RCH + rc) * (V_ * V_) + p];
        Ss[p] = s * (1.0f / (IC_ * T_));
    }
    __syncthreads();
    if (tid < V_) {
        const int v = tid;
        float m = -1e30f;
#pragma unroll
        for (int u = 0; u < V_; ++u) m = fmaxf(m, Ss[u * V_ + v]);
        float e[V_]; float es = 0.f;
#pragma unroll
        for (int u = 0; u < V_; ++u) { e[u] = expf(Ss[u * V_ + v] - m); es += e[u]; }
        const float inv = 1.0f / es;
#pragma unroll
        for (int u = 0; u < V_; ++u)
            a1o[n * (V_ * V_) + u * V_ + v] = afull[u * V_ + v] + e[u] * inv;
    }
}

// ---- kernel C: fused (x@A1_i) -> 1x1 conv, all 3 subsets + BN + res + relu -
// thread=(t,v), z[64] register accumulators; 1x1 weights via scalar loads
__global__ __launch_bounds__(256) void agg_out_kernel(
    const float* __restrict__ x,   const float* __restrict__ a1,
    const float* __restrict__ wds, const float* __restrict__ bdt,
    const float* __restrict__ bna, const float* __restrict__ bnb,
    float* __restrict__ out)
{
    __shared__ __align__(16) float xs[CC_C * TT_C * XPAD];  // 35 KB, padded rows
    __shared__ float A1s[S_ * V_ * V_];                     // 7.5 KB
    const int tid = threadIdx.x;
    const int n   = blockIdx.y;
    const int t0  = blockIdx.x * TT_C;
    for (int idx = tid; idx < S_ * V_ * V_; idx += 256) {
        int i = idx / (V_ * V_);
        A1s[idx] = a1[(i * N_ + n) * (V_ * V_) + (idx - i * (V_ * V_))];
    }
    const int tl = tid / V_;
    const int v  = tid % V_;
    float z[C_];
#pragma unroll
    for (int o = 0; o < C_; ++o) z[o] = 0.f;

    for (int ch = 0; ch < C_ / CC_C; ++ch) {
        __syncthreads();
        for (int idx = tid; idx < CC_C * TT_C * V_; idx += 256) {
            int c   = idx / (TT_C * V_);
            int rem = idx % (TT_C * V_);
            int tr  = rem / V_;
            int vv  = rem % V_;
            xs[(c * TT_C + tr) * XPAD + vv] =
                x[((n * C_ + ch * CC_C + c) * T_ + t0) * V_ + rem];
        }
        __syncthreads();
        if (tl < TT_C) {
            for (int i = 0; i < S_; ++i) {
                float a1c[V_];
#pragma unroll
                for (int u = 0; u < V_; ++u) a1c[u] = A1s[i * (V_ * V_) + u * V_ + v];
                const float* __restrict__ wbase = wds + (i * C_ + ch * CC_C) * C_;
                for (int c = 0; c < CC_C; ++c) {
                    const float* __restrict__ xr = xs + (c * TT_C + tl) * XPAD;
                    float a = 0.f;
#pragma unroll
                    for (int u = 0; u < V_; ++u) a = fmaf(xr[u], a1c[u], a);
                    const float* __restrict__ wp = wbase + c * C_;
#pragma unroll
                    for (int o = 0; o < C_; ++o) z[o] = fmaf(wp[o], a, z[o]);
                }
            }
        }
    }
    if (tl < TT_C) {
        const int tg = t0 + tl;
#pragma unroll
        for (int o = 0; o < C_; ++o) {
            float val = z[o] + bdt[o];
            val = fmaf(val, bna[o], bnb[o]);
            val += x[((n * C_ + o) * T_ + tg) * V_ + v];
            out[((n * C_ + o) * T_ + tg) * V_ + v] = fmaxf(val, 0.f);
        }
    }
}

// ---- launch ----------------------------------------------------------------
extern "C" void kernel_launch(void* const* d_in, const int* in_sizes, int n_in,
                              void* d_out, int out_size, void* d_ws, size_t ws_size,
                              hipStream_t stream)
{
    (void)in_sizes; (void)n_in; (void)out_size; (void)ws_size;  // ws need: ~63.5 MB
    const float* x    = (const float*)d_in[0];
    const float* wv   = (const float*)d_in[1];
    const float* A    = (const float*)d_in[2];
    const float* PA   = (const float*)d_in[3];
    const float* Wd   = (const float*)d_in[4];
    const float* bd   = (const float*)d_in[5];
    const float* WT1  = (const float*)d_in[6];
    const float* bT1  = (const float*)d_in[7];
    const float* WT2  = (const float*)d_in[8];
    const float* bT2  = (const float*)d_in[9];
    const float* gam  = (const float*)d_in[10];
    const float* bet  = (const float*)d_in[11];
    const float* mu   = (const float*)d_in[12];
    const float* var  = (const float*)d_in[13];
    float* ws  = (float*)d_ws;
    float* out = (float*)d_out;

    prep_kernel<<<dim3(64), dim3(256), 0, stream>>>(
        wv, A, PA, Wd, bd, WT1, bT1, WT2, bT2, gam, bet, mu, var, ws);

    for (int i = 0; i < S_; ++i) {
        tconv_kernel<<<dim3(T_ / TT_A, N_), dim3(256), 0, stream>>>(
            x,
            ws + OFF_W1S + i * (C_ * KT_ * IC_),
            ws + OFF_W2S + i * (C_ * KT_ * IC_),
            ws + OFF_BT1 + i * IC_,
            ws + OFF_BT2 + i * IC_,
            ws + OFF_T1, ws + OFF_T2);
        att_partial_kernel<<<dim3(RCH, N_), dim3(256), 0, stream>>>(
            ws + OFF_T1, ws + OFF_T2, ws + OFF_SPART);
        att_softmax_kernel<<<dim3(N_), dim3(256), 0, stream>>>(
            ws + OFF_SPART, ws + OFF_AFULL + i * (V_ * V_),
            ws + OFF_A1 + i * (N_ * V_ * V_));
    }

    agg_out_kernel<<<dim3(T_ / TT_C, N_), dim3(256), 0, stream>>>(
        x, ws + OFF_A1, ws + OFF_WDS, ws + OFF_BDT, ws + OFF_BNA, ws + OFF_BNB, out);
}

// Round 2
// 872.143 us; speedup vs baseline: 1.7194x; 1.7194x over previous
//
#include <hip/hip_runtime.h>

// ---- problem constants -----------------------------------------------------
constexpr int N_ = 64, C_ = 64, T_ = 300, V_ = 25, IC_ = 16, S_ = 3, KT_ = 9;
constexpr int RCH = 8, RSUB = 60;       // attention split-K chunks / LDS sub-chunk rows
constexpr int TT_C = 10, CC_C = 32;     // agg_out: t-tile, channel chunk
constexpr int XPAD = 28;                // padded LDS row stride for agg_out

// ---- tconv MFMA tiling ------------------------------------------------------
constexpr int TTM   = 16;               // t-steps per block
constexpr int SROWS = TTM + 8;          // staged t rows (halo 4+4)
constexpr int MROWS = SROWS * V_;       // 600 staged patch rows
constexpr int CSTR  = 40;               // LDS row stride in bf16 (32 data + 8 pad)
constexpr int NTB   = (T_ + TTM - 1) / TTM;  // 19 t-blocks

typedef __bf16 bf16x8 __attribute__((ext_vector_type(8)));
typedef float  f32x4  __attribute__((ext_vector_type(4)));

// ---- workspace layout (floats); total ~15.84M floats ~= 63.4 MB -------------
constexpr int OFF_AFULL = 0;
constexpr int SZ_AFULL  = S_ * V_ * V_;                 // 1875
constexpr int OFF_WTB   = OFF_AFULL + SZ_AFULL;         // bf16 S*9*32*64 = 55296 elems
constexpr int SZ_WTB_F  = (S_ * KT_ * 32 * C_) / 2;     // 27648 float-slots
constexpr int OFF_BTC   = OFF_WTB + SZ_WTB_F;           // S*32 fp32 biases
constexpr int OFF_WDS   = OFF_BTC + S_ * 32;
constexpr int SZ_WDS    = S_ * C_ * C_;                 // 12288, layout [i][c][o]
constexpr int OFF_BDT   = OFF_WDS + SZ_WDS;             // C
constexpr int OFF_BNA   = OFF_BDT + C_;
constexpr int OFF_BNB   = OFF_BNA + C_;
constexpr int OFF_A1    = OFF_BNB + C_;
constexpr int SZ_A1     = S_ * N_ * V_ * V_;            // 120000
constexpr int OFF_SPART = OFF_A1 + SZ_A1;
constexpr int SZ_SPART  = N_ * RCH * V_ * V_;           // 320000
constexpr int OFF_T1    = OFF_SPART + SZ_SPART;
constexpr int SZ_T      = N_ * IC_ * T_ * V_;           // 7680000
constexpr int OFF_T2    = OFF_T1 + SZ_T;

// SlimConv2d channel scales: splits at int(0.6/0.7/0.8/0.9 * out_c)
__device__ __forceinline__ float slim16(const float* w, int o) {
    if (o < 9)  return 1.0f;
    if (o < 11) return w[1];
    if (o < 12) return w[2];
    if (o < 14) return w[3];
    return w[4];
}
__device__ __forceinline__ float slim64(const float* w, int o) {
    if (o < 38) return 1.0f;
    if (o < 44) return w[1];
    if (o < 51) return w[2];
    if (o < 57) return w[3];
    return w[4];
}

// ---- prep: A_full, packed bf16 t-conv weights, folded biases, BN affine -----
__global__ void prep_kernel(const float* __restrict__ wv,  const float* __restrict__ A,
                            const float* __restrict__ PA,  const float* __restrict__ Wd,
                            const float* __restrict__ bd,  const float* __restrict__ WT1,
                            const float* __restrict__ bT1, const float* __restrict__ WT2,
                            const float* __restrict__ bT2, const float* __restrict__ gam,
                            const float* __restrict__ bet, const float* __restrict__ mu,
                            const float* __restrict__ var, float* __restrict__ ws)
{
    const int gid = blockIdx.x * blockDim.x + threadIdx.x;
    const int stride = gridDim.x * blockDim.x;
    // A_full = A + PA + 8A^4 - 4A^2 - 4A + I (elementwise powers)
    for (int idx = gid; idx < S_ * V_ * V_; idx += stride) {
        int uv = idx % (V_ * V_);
        int u = uv / V_, v = uv % V_;
        float a  = A[idx];
        float a2 = a * a;
        ws[OFF_AFULL + idx] = a + PA[idx] + 8.f * a2 * a2 - 4.f * a2 - 4.f * a
                              + (u == v ? 1.f : 0.f);
    }
    // t-conv weights: scaled bf16, layout [i][kt][o32][c] (o<16: WT1, o>=16: WT2)
    {
        __bf16* wtb = (__bf16*)(ws + OFF_WTB);
        for (int idx = gid; idx < S_ * KT_ * 32 * C_; idx += stride) {
            int c  = idx % C_;
            int r  = idx / C_;
            int o  = r % 32;  r /= 32;
            int kt = r % KT_;
            int i  = r / KT_;
            float val;
            if (o < IC_)
                val = slim16(wv, o) * WT1[((i * IC_ + o) * C_ + c) * KT_ + kt];
            else
                val = slim16(wv, o - IC_) * WT2[((i * IC_ + (o - IC_)) * C_ + c) * KT_ + kt];
            wtb[idx] = (__bf16)val;
        }
    }
    // combined scaled t-conv biases [i][o32]
    for (int idx = gid; idx < S_ * 32; idx += stride) {
        int i = idx / 32, o = idx % 32;
        float val = (o < IC_) ? slim16(wv, o) * bT1[i * IC_ + o]
                              : slim16(wv, o - IC_) * bT2[i * IC_ + (o - IC_)];
        ws[OFF_BTC + idx] = val;
    }
    // 1x1 conv weights, scaled, transposed to [i][c][o]
    for (int idx = gid; idx < SZ_WDS; idx += stride) {
        int o = idx % C_;
        int c = (idx / C_) % C_;
        int i = idx / (C_ * C_);
        ws[OFF_WDS + idx] = slim64(wv, o) * Wd[(i * C_ + o) * C_ + c];
    }
    // summed scaled 1x1 bias + BN affine
    for (int idx = gid; idx < C_; idx += stride) {
        float bt = 0.f;
        for (int i = 0; i < S_; ++i) bt += slim64(wv, idx) * bd[i * C_ + idx];
        ws[OFF_BDT + idx] = bt;
        float ba = gam[idx] * rsqrtf(var[idx] + 1e-5f);
        ws[OFF_BNA + idx] = ba;
        ws[OFF_BNB + idx] = bet[idx] - mu[idx] * ba;
    }
}

// ---- kernel A: both temporal convs via MFMA implicit GEMM -------------------
// D[o=32][m=(t,v)] = sum_{kt,c} Wt[kt][o][c] * x[n][c][t-4+kt][v]
// block: one n, 16 t (400 m rows = 25 M-tiles); 5 waves x 5 tiles each.
// xs[(s*25+v)][c] bf16, stride 40: B-frag row for (m,kt) is m + 25*kt.
__global__ __launch_bounds__(320) void tconv_mfma_kernel(
    const float* __restrict__ x,  const __bf16* __restrict__ wt,
    const float* __restrict__ bias32,
    float* __restrict__ t1o, float* __restrict__ t2o)
{
    __shared__ __align__(16) __bf16 xs[MROWS * CSTR];   // 24000 bf16 = 48 KB
    const int tid  = threadIdx.x;
    const int n    = blockIdx.y;
    const int t0   = blockIdx.x * TTM;
    const int wv   = tid >> 6;          // wave 0..4
    const int lane = tid & 63;
    const int l15  = lane & 15;
    const int quad = lane >> 4;

    f32x4 acc[5][2];
#pragma unroll
    for (int j = 0; j < 5; ++j)
#pragma unroll
        for (int p = 0; p < 2; ++p) acc[j][p] = (f32x4){0.f, 0.f, 0.f, 0.f};

    for (int ch = 0; ch < 2; ++ch) {
        const int c0 = ch * 32;
        __syncthreads();
        // stage xs: 600 rows x 32 c (bf16), vectorized 8-c groups (16B LDS writes)
        for (int idx = tid; idx < MROWS * 4; idx += 320) {
            const int lr = idx % MROWS;       // s*25 + v
            const int cg = idx / MROWS;       // c-group of 8
            const int tg = t0 - 4 + lr / V_;
            bf16x8 pk;
            if (tg >= 0 && tg < T_) {
                const float* gp = x + ((size_t)(n * C_ + c0 + cg * 8) * T_ + (t0 - 4)) * V_ + lr;
#pragma unroll
                for (int jj = 0; jj < 8; ++jj) pk[jj] = (__bf16)gp[(size_t)jj * T_ * V_];
            } else {
#pragma unroll
                for (int jj = 0; jj < 8; ++jj) pk[jj] = (__bf16)0.f;
            }
            *(bf16x8*)&xs[lr * CSTR + cg * 8] = pk;
        }
        __syncthreads();

        for (int kt = 0; kt < KT_; ++kt) {
            // A-frags: weights straight from global (L1-resident, 18 KB/chunk)
            const bf16x8 a0 = *(const bf16x8*)&wt[(kt * 32 + l15) * C_ + c0 + quad * 8];
            const bf16x8 a1 = *(const bf16x8*)&wt[(kt * 32 + 16 + l15) * C_ + c0 + quad * 8];
#pragma unroll
            for (int j = 0; j < 5; ++j) {
                const int r = (wv * 5 + j) * 16 + l15 + V_ * kt;
                const bf16x8 b = *(const bf16x8*)&xs[r * CSTR + quad * 8];
                acc[j][0] = __builtin_amdgcn_mfma_f32_16x16x32_bf16(a0, b, acc[j][0], 0, 0, 0);
                acc[j][1] = __builtin_amdgcn_mfma_f32_16x16x32_bf16(a1, b, acc[j][1], 0, 0, 0);
            }
        }
    }

    // epilogue: D col = lane&15 = m_local, row = quad*4+r = o_local
#pragma unroll
    for (int j = 0; j < 5; ++j) {
        const int m = (wv * 5 + j) * 16 + l15;
        const int t = t0 + m / V_;
        const int v = m % V_;
        if (t < T_) {
#pragma unroll
            for (int p = 0; p < 2; ++p) {
#pragma unroll
                for (int r = 0; r < 4; ++r) {
                    const int o = p * 16 + quad * 4 + r;
                    const float val = acc[j][p][r] + bias32[o];
                    if (o < IC_)
                        t1o[((n * IC_ + o) * T_ + t) * V_ + v] = val;
                    else
                        t2o[((n * IC_ + (o - IC_)) * T_ + t) * V_ + v] = val;
                }
            }
        }
    }
}

// ---- kernel B1: attention partial sums S[u,v] over 600-row chunks ----------
__global__ __launch_bounds__(256) void att_partial_kernel(
    const float* __restrict__ t1, const float* __restrict__ t2,
    float* __restrict__ spart)
{
    __shared__ float t1s[RSUB * V_];
    __shared__ float t2s[RSUB * V_];
    const int tid = threadIdx.x;
    const int rc  = blockIdx.x;
    const int n   = blockIdx.y;
    const int p0 = tid, p1 = tid + 256, p2 = tid + 512;
    const int p2c = (p2 < V_ * V_) ? p2 : (V_ * V_ - 1);
    const int u0 = p0 / V_, v0 = p0 % V_;
    const int u1 = p1 / V_, v1 = p1 % V_;
    const int u2 = p2c / V_, v2 = p2c % V_;
    float a0 = 0.f, a1 = 0.f, a2 = 0.f;
    const int rows = (IC_ * T_) / RCH;                       // 600
    const float* g1 = t1 + n * (IC_ * T_ * V_) + rc * rows * V_;
    const float* g2 = t2 + n * (IC_ * T_ * V_) + rc * rows * V_;
    for (int sc = 0; sc < rows / RSUB; ++sc) {
        __syncthreads();
        for (int idx = tid; idx < RSUB * V_; idx += 256) {
            t1s[idx] = g1[sc * RSUB * V_ + idx];
            t2s[idx] = g2[sc * RSUB * V_ + idx];
        }
        __syncthreads();
        for (int r = 0; r < RSUB; ++r) {
            const float* r1 = t1s + r * V_;
            const float* r2 = t2s + r * V_;
            a0 = fmaf(r1[u0], r2[v0], a0);
            a1 = fmaf(r1[u1], r2[v1], a1);
            a2 = fmaf(r1[u2], r2[v2], a2);
        }
    }
    float* sp = spart + (n * RCH + rc) * (V_ * V_);
    sp[p0] = a0;
    sp[p1] = a1;
    if (p2 < V_ * V_) sp[p2] = a2;
}

// ---- kernel B2: combine partials, softmax over u (axis=-2), add A_full -----
__global__ __launch_bounds__(256) void att_softmax_kernel(
    const float* __restrict__ spart, const float* __restrict__ afull,
    float* __restrict__ a1o)
{
    __shared__ float Ss[V_ * V_];
    const int n = blockIdx.x;
    const int tid = threadIdx.x;
    for (int p = tid; p < V_ * V_; p += 256) {
        float s = 0.f;
        for (int rc = 0; rc < RCH; ++rc)
            s += spart[(n * RCH + rc) * (V_ * V_) + p];
        Ss[p] = s * (1.0f / (IC_ * T_));
    }
    __syncthreads();
    if (tid < V_) {
        const int v = tid;
        float m = -1e30f;
#pragma unroll
        for (int u = 0; u < V_; ++u) m = fmaxf(m, Ss[u * V_ + v]);
        float e[V_]; float es = 0.f;
#pragma unroll
        for (int u = 0; u < V_; ++u) { e[u] = expf(Ss[u * V_ + v] - m); es += e[u]; }
        const float inv = 1.0f / es;
#pragma unroll
        for (int u = 0; u < V_; ++u)
            a1o[n * (V_ * V_) + u * V_ + v] = afull[u * V_ + v] + e[u] * inv;
    }
}

// ---- kernel C: fused (x@A1_i) -> 1x1 conv, all 3 subsets + BN + res + relu -
__global__ __launch_bounds__(256) void agg_out_kernel(
    const float* __restrict__ x,   const float* __restrict__ a1,
    const float* __restrict__ wds, const float* __restrict__ bdt,
    const float* __restrict__ bna, const float* __restrict__ bnb,
    float* __restrict__ out)
{
    __shared__ __align__(16) float xs[CC_C * TT_C * XPAD];  // 35 KB, padded rows
    __shared__ float A1s[S_ * V_ * V_];                     // 7.5 KB
    const int tid = threadIdx.x;
    const int n   = blockIdx.y;
    const int t0  = blockIdx.x * TT_C;
    for (int idx = tid; idx < S_ * V_ * V_; idx += 256) {
        int i = idx / (V_ * V_);
        A1s[idx] = a1[(i * N_ + n) * (V_ * V_) + (idx - i * (V_ * V_))];
    }
    const int tl = tid / V_;
    const int v  = tid % V_;
    float z[C_];
#pragma unroll
    for (int o = 0; o < C_; ++o) z[o] = 0.f;

    for (int ch = 0; ch < C_ / CC_C; ++ch) {
        __syncthreads();
        for (int idx = tid; idx < CC_C * TT_C * V_; idx += 256) {
            int c   = idx / (TT_C * V_);
            int rem = idx % (TT_C * V_);
            int tr  = rem / V_;
            int vv  = rem % V_;
            xs[(c * TT_C + tr) * XPAD + vv] =
                x[((n * C_ + ch * CC_C + c) * T_ + t0) * V_ + rem];
        }
        __syncthreads();
        if (tl < TT_C) {
            for (int i = 0; i < S_; ++i) {
                float a1c[V_];
#pragma unroll
                for (int u = 0; u < V_; ++u) a1c[u] = A1s[i * (V_ * V_) + u * V_ + v];
                const float* __restrict__ wbase = wds + (i * C_ + ch * CC_C) * C_;
                for (int c = 0; c < CC_C; ++c) {
                    const float* __restrict__ xr = xs + (c * TT_C + tl) * XPAD;
                    float a = 0.f;
#pragma unroll
                    for (int u = 0; u < V_; ++u) a = fmaf(xr[u], a1c[u], a);
                    const float* __restrict__ wp = wbase + c * C_;
#pragma unroll
                    for (int o = 0; o < C_; ++o) z[o] = fmaf(wp[o], a, z[o]);
                }
            }
        }
    }
    if (tl < TT_C) {
        const int tg = t0 + tl;
#pragma unroll
        for (int o = 0; o < C_; ++o) {
            float val = z[o] + bdt[o];
            val = fmaf(val, bna[o], bnb[o]);
            val += x[((n * C_ + o) * T_ + tg) * V_ + v];
            out[((n * C_ + o) * T_ + tg) * V_ + v] = fmaxf(val, 0.f);
        }
    }
}

// ---- launch ----------------------------------------------------------------
extern "C" void kernel_launch(void* const* d_in, const int* in_sizes, int n_in,
                              void* d_out, int out_size, void* d_ws, size_t ws_size,
                              hipStream_t stream)
{
    (void)in_sizes; (void)n_in; (void)out_size; (void)ws_size;
    const float* x    = (const float*)d_in[0];
    const float* wv   = (const float*)d_in[1];
    const float* A    = (const float*)d_in[2];
    const float* PA   = (const float*)d_in[3];
    const float* Wd   = (const float*)d_in[4];
    const float* bd   = (const float*)d_in[5];
    const float* WT1  = (const float*)d_in[6];
    const float* bT1  = (const float*)d_in[7];
    const float* WT2  = (const float*)d_in[8];
    const float* bT2  = (const float*)d_in[9];
    const float* gam  = (const float*)d_in[10];
    const float* bet  = (const float*)d_in[11];
    const float* mu   = (const float*)d_in[12];
    const float* var  = (const float*)d_in[13];
    float* ws  = (float*)d_ws;
    float* out = (float*)d_out;

    prep_kernel<<<dim3(64), dim3(256), 0, stream>>>(
        wv, A, PA, Wd, bd, WT1, bT1, WT2, bT2, gam, bet, mu, var, ws);

    const __bf16* wtb = (const __bf16*)(ws + OFF_WTB);
    for (int i = 0; i < S_; ++i) {
        tconv_mfma_kernel<<<dim3(NTB, N_), dim3(320), 0, stream>>>(
            x,
            wtb + (size_t)i * KT_ * 32 * C_,
            ws + OFF_BTC + i * 32,
            ws + OFF_T1, ws + OFF_T2);
        att_partial_kernel<<<dim3(RCH, N_), dim3(256), 0, stream>>>(
            ws + OFF_T1, ws + OFF_T2, ws + OFF_SPART);
        att_softmax_kernel<<<dim3(N_), dim3(256), 0, stream>>>(
            ws + OFF_SPART, ws + OFF_AFULL + i * (V_ * V_),
            ws + OFF_A1 + i * (N_ * V_ * V_));
    }

    agg_out_kernel<<<dim3(T_ / TT_C, N_), dim3(256), 0, stream>>>(
        x, ws + OFF_A1, ws + OFF_WDS, ws + OFF_BDT, ws + OFF_BNA, ws + OFF_BNB, out);
}

// Round 3
// 842.008 us; speedup vs baseline: 1.7810x; 1.0358x over previous
//
#include <hip/hip_runtime.h>

// ---- problem constants -----------------------------------------------------
constexpr int N_ = 64, C_ = 64, T_ = 300, V_ = 25, IC_ = 16, S_ = 3, KT_ = 9;
constexpr int RCH = 8, RSUB = 60;       // attention split-K chunks / LDS sub-chunk rows

// ---- tconv MFMA tiling ------------------------------------------------------
constexpr int TTM   = 16;               // t-steps per block
constexpr int SROWS = TTM + 8;          // staged t rows (halo 4+4)
constexpr int MROWS = SROWS * V_;       // 600 staged patch rows
constexpr int CSTR  = 40;               // LDS row stride in bf16 (32 data + 8 pad)
constexpr int NTB   = (T_ + TTM - 1) / TTM;  // 19 t-blocks

// ---- agg_out MFMA tiling ----------------------------------------------------
constexpr int TTZ   = 16;               // t-steps per block
constexpr int NTBZ  = (T_ + TTZ - 1) / TTZ;  // 19
constexpr int ASTR  = 36;               // ags row stride (32 c + 4 pad), bf16

typedef __bf16 bf16x8 __attribute__((ext_vector_type(8)));
typedef __bf16 bf16x4 __attribute__((ext_vector_type(4)));
typedef float  f32x4  __attribute__((ext_vector_type(4)));

// ---- workspace layout (floats) ----------------------------------------------
constexpr int OFF_AFULL = 0;
constexpr int SZ_AFULL  = S_ * V_ * V_;                 // 1875
constexpr int OFF_WTB   = OFF_AFULL + SZ_AFULL;         // bf16 S*9*32*64
constexpr int SZ_WTB_F  = (S_ * KT_ * 32 * C_) / 2;     // 27648 float-slots
constexpr int OFF_BTC   = OFF_WTB + SZ_WTB_F;           // S*32 fp32 biases
constexpr int OFF_WDB   = OFF_BTC + S_ * 32;            // bf16 S*64*64 [i][o][c]
constexpr int SZ_WDB_F  = (S_ * C_ * C_) / 2;           // 6144 float-slots
constexpr int OFF_BDT   = OFF_WDB + SZ_WDB_F;           // C
constexpr int OFF_BNA   = OFF_BDT + C_;
constexpr int OFF_BNB   = OFF_BNA + C_;
constexpr int OFF_A1    = OFF_BNB + C_;
constexpr int SZ_A1     = S_ * N_ * V_ * V_;            // 120000  [i][n][u][v] fp32
constexpr int OFF_SPART = OFF_A1 + SZ_A1;
constexpr int SZ_SPART  = N_ * RCH * V_ * V_;           // 320000
constexpr int OFF_T1    = OFF_SPART + SZ_SPART;
constexpr int SZ_T_F    = (N_ * IC_ * T_ * V_) / 2;     // bf16 now: 3.84M float-slots
constexpr int OFF_T2    = OFF_T1 + SZ_T_F;

// SlimConv2d channel scales: splits at int(0.6/0.7/0.8/0.9 * out_c)
__device__ __forceinline__ float slim16(const float* w, int o) {
    if (o < 9)  return 1.0f;
    if (o < 11) return w[1];
    if (o < 12) return w[2];
    if (o < 14) return w[3];
    return w[4];
}
__device__ __forceinline__ float slim64(const float* w, int o) {
    if (o < 38) return 1.0f;
    if (o < 44) return w[1];
    if (o < 51) return w[2];
    if (o < 57) return w[3];
    return w[4];
}

// ---- prep: A_full, packed bf16 weights, folded biases, BN affine ------------
__global__ void prep_kernel(const float* __restrict__ wv,  const float* __restrict__ A,
                            const float* __restrict__ PA,  const float* __restrict__ Wd,
                            const float* __restrict__ bd,  const float* __restrict__ WT1,
                            const float* __restrict__ bT1, const float* __restrict__ WT2,
                            const float* __restrict__ bT2, const float* __restrict__ gam,
                            const float* __restrict__ bet, const float* __restrict__ mu,
                            const float* __restrict__ var, float* __restrict__ ws)
{
    const int gid = blockIdx.x * blockDim.x + threadIdx.x;
    const int stride = gridDim.x * blockDim.x;
    // A_full = A + PA + 8A^4 - 4A^2 - 4A + I (elementwise powers)
    for (int idx = gid; idx < S_ * V_ * V_; idx += stride) {
        int uv = idx % (V_ * V_);
        int u = uv / V_, v = uv % V_;
        float a  = A[idx];
        float a2 = a * a;
        ws[OFF_AFULL + idx] = a + PA[idx] + 8.f * a2 * a2 - 4.f * a2 - 4.f * a
                              + (u == v ? 1.f : 0.f);
    }
    // t-conv weights: scaled bf16, layout [i][kt][o32][c]
    {
        __bf16* wtb = (__bf16*)(ws + OFF_WTB);
        for (int idx = gid; idx < S_ * KT_ * 32 * C_; idx += stride) {
            int c  = idx % C_;
            int r  = idx / C_;
            int o  = r % 32;  r /= 32;
            int kt = r % KT_;
            int i  = r / KT_;
            float val;
            if (o < IC_)
                val = slim16(wv, o) * WT1[((i * IC_ + o) * C_ + c) * KT_ + kt];
            else
                val = slim16(wv, o - IC_) * WT2[((i * IC_ + (o - IC_)) * C_ + c) * KT_ + kt];
            wtb[idx] = (__bf16)val;
        }
    }
    // combined scaled t-conv biases [i][o32]
    for (int idx = gid; idx < S_ * 32; idx += stride) {
        int i = idx / 32, o = idx % 32;
        float val = (o < IC_) ? slim16(wv, o) * bT1[i * IC_ + o]
                              : slim16(wv, o - IC_) * bT2[i * IC_ + (o - IC_)];
        ws[OFF_BTC + idx] = val;
    }
    // 1x1 conv weights: scaled bf16, [i][o][c] (A-frag layout for GEMM2)
    {
        __bf16* wdb = (__bf16*)(ws + OFF_WDB);
        for (int idx = gid; idx < S_ * C_ * C_; idx += stride) {
            int c = idx % C_;
            int o = (idx / C_) % C_;
            int i = idx / (C_ * C_);
            wdb[idx] = (__bf16)(slim64(wv, o) * Wd[(i * C_ + o) * C_ + c]);
        }
    }
    // summed scaled 1x1 bias + BN affine
    for (int idx = gid; idx < C_; idx += stride) {
        float bt = 0.f;
        for (int i = 0; i < S_; ++i) bt += slim64(wv, idx) * bd[i * C_ + idx];
        ws[OFF_BDT + idx] = bt;
        float ba = gam[idx] * rsqrtf(var[idx] + 1e-5f);
        ws[OFF_BNA + idx] = ba;
        ws[OFF_BNB + idx] = bet[idx] - mu[idx] * ba;
    }
}

// ---- kernel A: both temporal convs via MFMA implicit GEMM -------------------
__global__ __launch_bounds__(320) void tconv_mfma_kernel(
    const float* __restrict__ x,  const __bf16* __restrict__ wt,
    const float* __restrict__ bias32,
    __bf16* __restrict__ t1o, __bf16* __restrict__ t2o)
{
    __shared__ __align__(16) __bf16 xs[MROWS * CSTR];   // 48 KB
    const int tid  = threadIdx.x;
    const int n    = blockIdx.y;
    const int t0   = blockIdx.x * TTM;
    const int wv   = tid >> 6;
    const int lane = tid & 63;
    const int l15  = lane & 15;
    const int quad = lane >> 4;

    f32x4 acc[5][2];
#pragma unroll
    for (int j = 0; j < 5; ++j)
#pragma unroll
        for (int p = 0; p < 2; ++p) acc[j][p] = (f32x4){0.f, 0.f, 0.f, 0.f};

    for (int ch = 0; ch < 2; ++ch) {
        const int c0 = ch * 32;
        __syncthreads();
        for (int idx = tid; idx < MROWS * 4; idx += 320) {
            const int lr = idx % MROWS;
            const int cg = idx / MROWS;
            const int tg = t0 - 4 + lr / V_;
            bf16x8 pk;
            if (tg >= 0 && tg < T_) {
                const float* gp = x + ((size_t)(n * C_ + c0 + cg * 8) * T_ + (t0 - 4)) * V_ + lr;
#pragma unroll
                for (int jj = 0; jj < 8; ++jj) pk[jj] = (__bf16)gp[(size_t)jj * T_ * V_];
            } else {
#pragma unroll
                for (int jj = 0; jj < 8; ++jj) pk[jj] = (__bf16)0.f;
            }
            *(bf16x8*)&xs[lr * CSTR + cg * 8] = pk;
        }
        __syncthreads();

        for (int kt = 0; kt < KT_; ++kt) {
            const bf16x8 a0 = *(const bf16x8*)&wt[(kt * 32 + l15) * C_ + c0 + quad * 8];
            const bf16x8 a1 = *(const bf16x8*)&wt[(kt * 32 + 16 + l15) * C_ + c0 + quad * 8];
#pragma unroll
            for (int j = 0; j < 5; ++j) {
                const int r = (wv * 5 + j) * 16 + l15 + V_ * kt;
                const bf16x8 b = *(const bf16x8*)&xs[r * CSTR + quad * 8];
                acc[j][0] = __builtin_amdgcn_mfma_f32_16x16x32_bf16(a0, b, acc[j][0], 0, 0, 0);
                acc[j][1] = __builtin_amdgcn_mfma_f32_16x16x32_bf16(a1, b, acc[j][1], 0, 0, 0);
            }
        }
    }

#pragma unroll
    for (int j = 0; j < 5; ++j) {
        const int m = (wv * 5 + j) * 16 + l15;
        const int t = t0 + m / V_;
        const int v = m % V_;
        if (t < T_) {
#pragma unroll
            for (int p = 0; p < 2; ++p) {
#pragma unroll
                for (int r = 0; r < 4; ++r) {
                    const int o = p * 16 + quad * 4 + r;
                    const float val = acc[j][p][r] + bias32[o];
                    if (o < IC_)
                        t1o[((n * IC_ + o) * T_ + t) * V_ + v] = (__bf16)val;
                    else
                        t2o[((n * IC_ + (o - IC_)) * T_ + t) * V_ + v] = (__bf16)val;
                }
            }
        }
    }
}

// ---- kernel B1: attention partial sums S[u,v] over 600-row chunks ----------
__global__ __launch_bounds__(256) void att_partial_kernel(
    const __bf16* __restrict__ t1, const __bf16* __restrict__ t2,
    float* __restrict__ spart)
{
    __shared__ float t1s[RSUB * V_];
    __shared__ float t2s[RSUB * V_];
    const int tid = threadIdx.x;
    const int rc  = blockIdx.x;
    const int n   = blockIdx.y;
    const int p0 = tid, p1 = tid + 256, p2 = tid + 512;
    const int p2c = (p2 < V_ * V_) ? p2 : (V_ * V_ - 1);
    const int u0 = p0 / V_, v0 = p0 % V_;
    const int u1 = p1 / V_, v1 = p1 % V_;
    const int u2 = p2c / V_, v2 = p2c % V_;
    float a0 = 0.f, a1 = 0.f, a2 = 0.f;
    const int rows = (IC_ * T_) / RCH;                       // 600
    const __bf16* g1 = t1 + (size_t)n * (IC_ * T_ * V_) + rc * rows * V_;
    const __bf16* g2 = t2 + (size_t)n * (IC_ * T_ * V_) + rc * rows * V_;
    for (int sc = 0; sc < rows / RSUB; ++sc) {
        __syncthreads();
        for (int idx = tid; idx < RSUB * V_; idx += 256) {
            t1s[idx] = (float)g1[sc * RSUB * V_ + idx];
            t2s[idx] = (float)g2[sc * RSUB * V_ + idx];
        }
        __syncthreads();
        for (int r = 0; r < RSUB; ++r) {
            const float* r1 = t1s + r * V_;
            const float* r2 = t2s + r * V_;
            a0 = fmaf(r1[u0], r2[v0], a0);
            a1 = fmaf(r1[u1], r2[v1], a1);
            a2 = fmaf(r1[u2], r2[v2], a2);
        }
    }
    float* sp = spart + (n * RCH + rc) * (V_ * V_);
    sp[p0] = a0;
    sp[p1] = a1;
    if (p2 < V_ * V_) sp[p2] = a2;
}

// ---- kernel B2: combine partials, softmax over u (axis=-2), add A_full -----
__global__ __launch_bounds__(256) void att_softmax_kernel(
    const float* __restrict__ spart, const float* __restrict__ afull,
    float* __restrict__ a1o)
{
    __shared__ float Ss[V_ * V_];
    const int n = blockIdx.x;
    const int tid = threadIdx.x;
    for (int p = tid; p < V_ * V_; p += 256) {
        float s = 0.f;
        for (int rc = 0; rc < RCH; ++rc)
            s += spart[(n * RCH + rc) * (V_ * V_) + p];
        Ss[p] = s * (1.0f / (IC_ * T_));
    }
    __syncthreads();
    if (tid < V_) {
        const int v = tid;
        float m = -1e30f;
#pragma unroll
        for (int u = 0; u < V_; ++u) m = fmaxf(m, Ss[u * V_ + v]);
        float e[V_]; float es = 0.f;
#pragma unroll
        for (int u = 0; u < V_; ++u) { e[u] = expf(Ss[u * V_ + v] - m); es += e[u]; }
        const float inv = 1.0f / es;
#pragma unroll
        for (int u = 0; u < V_; ++u)
            a1o[n * (V_ * V_) + u * V_ + v] = afull[u * V_ + v] + e[u] * inv;
    }
}

// ---- kernel C: fused (x@A1_i)->1x1 conv via 2-stage MFMA, +BN+res+relu ------
// GEMM1 per (c-chunk, subset): agg[s][v] = sum_u x[c][s][u]*A1[u][v]
//   A-frag rows = s from xt[c][s][u32], B-frag cols = v from a1t[v][u32].
//   D (col=v=l15, row=s=quad*4+r) scattered bf16 -> ags[s*25+v][c] (stride 36).
// GEMM2: z[o][m2] += Wd[i][o][c] * ags[c][m2], acc over all (chunk, subset).
__global__ __launch_bounds__(320) void agg_out_mfma_kernel(
    const float* __restrict__ x,   const float* __restrict__ a1,
    const __bf16* __restrict__ wdb, const float* __restrict__ bdt,
    const float* __restrict__ bna, const float* __restrict__ bnb,
    float* __restrict__ out)
{
    __shared__ __align__(16) __bf16 xt[32 * 16 * 32];   // [c][s][u32] 32 KB
    __shared__ __align__(16) __bf16 ags[400 * ASTR];    // 28.8 KB
    __shared__ __align__(16) __bf16 a1t[32 * 32];       // [v32][u32] 2 KB
    const int tid  = threadIdx.x;
    const int n    = blockIdx.y;
    const int t0   = blockIdx.x * TTZ;
    const int wv   = tid >> 6;
    const int lane = tid & 63;
    const int l15  = lane & 15;
    const int quad = lane >> 4;

    f32x4 acc[5][4];
#pragma unroll
    for (int j = 0; j < 5; ++j)
#pragma unroll
        for (int ot = 0; ot < 4; ++ot) acc[j][ot] = (f32x4){0.f, 0.f, 0.f, 0.f};

    for (int chunk = 0; chunk < 2; ++chunk) {
        const int c0 = chunk * 32;
        __syncthreads();   // xt free (prev GEMM1 done), ags free (prev GEMM2 done)
        // stage xt: groups of 4 u
        for (int idx = tid; idx < 32 * 16 * 8; idx += 320) {
            const int u4  = (idx & 7) * 4;
            const int row = idx >> 3;            // c*16 + s
            const int s   = row & 15;
            const int c   = row >> 4;
            const int t   = t0 + s;
            bf16x4 pk;
            if (t < T_) {
                const float* gp = x + ((size_t)(n * C_ + c0 + c) * T_ + t) * V_;
#pragma unroll
                for (int jj = 0; jj < 4; ++jj) {
                    const int u = u4 + jj;
                    pk[jj] = (u < V_) ? (__bf16)gp[u] : (__bf16)0.f;
                }
            } else {
#pragma unroll
                for (int jj = 0; jj < 4; ++jj) pk[jj] = (__bf16)0.f;
            }
            *(bf16x4*)&xt[row * 32 + u4] = pk;
        }
        for (int i = 0; i < S_; ++i) {
            __syncthreads();   // xt ready (first i); prev GEMM2 done reading ags
            // stage a1t transposed: a1t[v][u] = A1[i][n][u][v], zero-padded
            for (int idx = tid; idx < 1024; idx += 320) {
                const int v = idx >> 5, u = idx & 31;
                float val = (v < V_ && u < V_)
                          ? a1[((size_t)(i * N_ + n) * V_ + u) * V_ + v] : 0.f;
                a1t[idx] = (__bf16)val;
            }
            __syncthreads();   // a1t ready
            // GEMM1
            const bf16x8 b0 = *(const bf16x8*)&a1t[l15 * 32 + quad * 8];
            const bf16x8 b1 = *(const bf16x8*)&a1t[(16 + l15) * 32 + quad * 8];
            for (int c = wv; c < 32; c += 5) {
                const bf16x8 af = *(const bf16x8*)&xt[(c * 16 + l15) * 32 + quad * 8];
                f32x4 d0 = (f32x4){0.f, 0.f, 0.f, 0.f};
                f32x4 d1 = (f32x4){0.f, 0.f, 0.f, 0.f};
                d0 = __builtin_amdgcn_mfma_f32_16x16x32_bf16(af, b0, d0, 0, 0, 0);
                d1 = __builtin_amdgcn_mfma_f32_16x16x32_bf16(af, b1, d1, 0, 0, 0);
#pragma unroll
                for (int r = 0; r < 4; ++r) {
                    const int s = quad * 4 + r;
                    ags[(s * V_ + l15) * ASTR + c] = (__bf16)d0[r];
                    if (l15 < V_ - 16)
                        ags[(s * V_ + 16 + l15) * ASTR + c] = (__bf16)d1[r];
                }
            }
            __syncthreads();   // ags ready
            // GEMM2: A-frags from global (L1-resident)
            bf16x8 a2[4];
#pragma unroll
            for (int ot = 0; ot < 4; ++ot)
                a2[ot] = *(const bf16x8*)&wdb[(size_t)(i * C_ + ot * 16 + l15) * C_ + c0 + quad * 8];
#pragma unroll
            for (int j = 0; j < 5; ++j) {
                const int m2 = (wv * 5 + j) * 16 + l15;
                const bf16x4 lo = *(const bf16x4*)&ags[m2 * ASTR + quad * 8];
                const bf16x4 hi = *(const bf16x4*)&ags[m2 * ASTR + quad * 8 + 4];
                const bf16x8 b2 = __builtin_shufflevector(lo, hi, 0, 1, 2, 3, 4, 5, 6, 7);
#pragma unroll
                for (int ot = 0; ot < 4; ++ot)
                    acc[j][ot] = __builtin_amdgcn_mfma_f32_16x16x32_bf16(a2[ot], b2, acc[j][ot], 0, 0, 0);
            }
        }
    }

    // epilogue: D2 col = l15 = m2_local, row = quad*4+r = o_local
#pragma unroll
    for (int j = 0; j < 5; ++j) {
        const int m2 = (wv * 5 + j) * 16 + l15;
        const int s  = m2 / V_;
        const int v  = m2 % V_;
        const int t  = t0 + s;
        if (t < T_) {
#pragma unroll
            for (int ot = 0; ot < 4; ++ot) {
#pragma unroll
                for (int r = 0; r < 4; ++r) {
                    const int o = ot * 16 + quad * 4 + r;
                    float val = acc[j][ot][r] + bdt[o];
                    val = fmaf(val, bna[o], bnb[o]);
                    const size_t gi = ((size_t)(n * C_ + o) * T_ + t) * V_ + v;
                    val += x[gi];
                    out[gi] = fmaxf(val, 0.f);
                }
            }
        }
    }
}

// ---- launch ----------------------------------------------------------------
extern "C" void kernel_launch(void* const* d_in, const int* in_sizes, int n_in,
                              void* d_out, int out_size, void* d_ws, size_t ws_size,
                              hipStream_t stream)
{
    (void)in_sizes; (void)n_in; (void)out_size; (void)ws_size;
    const float* x    = (const float*)d_in[0];
    const float* wv   = (const float*)d_in[1];
    const float* A    = (const float*)d_in[2];
    const float* PA   = (const float*)d_in[3];
    const float* Wd   = (const float*)d_in[4];
    const float* bd   = (const float*)d_in[5];
    const float* WT1  = (const float*)d_in[6];
    const float* bT1  = (const float*)d_in[7];
    const float* WT2  = (const float*)d_in[8];
    const float* bT2  = (const float*)d_in[9];
    const float* gam  = (const float*)d_in[10];
    const float* bet  = (const float*)d_in[11];
    const float* mu   = (const float*)d_in[12];
    const float* var  = (const float*)d_in[13];
    float* ws  = (float*)d_ws;
    float* out = (float*)d_out;

    prep_kernel<<<dim3(64), dim3(256), 0, stream>>>(
        wv, A, PA, Wd, bd, WT1, bT1, WT2, bT2, gam, bet, mu, var, ws);

    const __bf16* wtb = (const __bf16*)(ws + OFF_WTB);
    __bf16* t1b = (__bf16*)(ws + OFF_T1);
    __bf16* t2b = (__bf16*)(ws + OFF_T2);
    for (int i = 0; i < S_; ++i) {
        tconv_mfma_kernel<<<dim3(NTB, N_), dim3(320), 0, stream>>>(
            x,
            wtb + (size_t)i * KT_ * 32 * C_,
            ws + OFF_BTC + i * 32,
            t1b, t2b);
        att_partial_kernel<<<dim3(RCH, N_), dim3(256), 0, stream>>>(
            t1b, t2b, ws + OFF_SPART);
        att_softmax_kernel<<<dim3(N_), dim3(256), 0, stream>>>(
            ws + OFF_SPART, ws + OFF_AFULL + i * (V_ * V_),
            ws + OFF_A1 + i * (N_ * V_ * V_));
    }

    agg_out_mfma_kernel<<<dim3(NTBZ, N_), dim3(320), 0, stream>>>(
        x, ws + OFF_A1, (const __bf16*)(ws + OFF_WDB),
        ws + OFF_BDT, ws + OFF_BNA, ws + OFF_BNB, out);
}